// Round 2
// 908.118 us; speedup vs baseline: 1.1646x; 1.1646x over previous
//
#include <hip/hip_runtime.h>

typedef __bf16 bf16;
typedef __bf16 bf16x8 __attribute__((ext_vector_type(8)));
typedef __bf16 bf16x4 __attribute__((ext_vector_type(4)));
typedef __bf16 bf16x2 __attribute__((ext_vector_type(2)));
typedef float f32x4 __attribute__((ext_vector_type(4)));
typedef float f32x16 __attribute__((ext_vector_type(16)));
typedef unsigned int u32x4 __attribute__((ext_vector_type(4)));

#define MFMA16(a, b, c) __builtin_amdgcn_mfma_f32_16x16x32_bf16(a, b, c, 0, 0, 0)
#define MFMA32(a, b, c) __builtin_amdgcn_mfma_f32_32x32x16_bf16(a, b, c, 0, 0, 0)

__device__ __forceinline__ void gload_lds16(const bf16* g, bf16* l) {
  __builtin_amdgcn_global_load_lds(
      (const __attribute__((address_space(1))) void*)g,
      (__attribute__((address_space(3))) void*)l, 16, 0, 0);
}

__device__ __forceinline__ unsigned pk2(float a, float b) {
  bf16x2 t;
  t[0] = (bf16)a;
  t[1] = (bf16)b;
  return __builtin_bit_cast(unsigned, t);
}

// ---------------------------------------------------------------------------
// f32 -> bf16 bulk convert, 8 elems/thread (32B load, 16B store)
__global__ __launch_bounds__(256) void f2b_k(const float* __restrict__ src,
                                             bf16* __restrict__ dst,
                                             long long n) {
  long long i = ((long long)blockIdx.x * 256 + threadIdx.x) * 8;
  if (i >= n) return;
  const float4 a = *(const float4*)(src + i);
  const float4 b = *(const float4*)(src + i + 4);
  bf16x8 v;
  v[0] = (bf16)a.x; v[1] = (bf16)a.y; v[2] = (bf16)a.z; v[3] = (bf16)a.w;
  v[4] = (bf16)b.x; v[5] = (bf16)b.y; v[6] = (bf16)b.z; v[7] = (bf16)b.w;
  *(bf16x8*)(dst + i) = v;
}

// ---------------------------------------------------------------------------
// Weight transpose+convert: Wt[n*K + k] = (bf16) W[k*N + n]
__global__ __launch_bounds__(256) void wconv_k(const float* __restrict__ W,
                                               bf16* __restrict__ Wt,
                                               int K, int N) {
  long long idx = (long long)blockIdx.x * 256 + threadIdx.x;
  if (idx >= (long long)K * N) return;
  int k = (int)(idx % K);
  int n = (int)(idx / K);
  Wt[idx] = (bf16)W[(long long)k * N + n];
}

// ---------------------------------------------------------------------------
// V transpose to padded per-frame layout:
// Vt[((bh*8+fr)*64 + d)*224 + k] = Vb[(bh*1568 + fr*196 + k)*64 + d], zero pad
__global__ __launch_bounds__(256) void transv_k(const bf16* __restrict__ Vb,
                                                bf16* __restrict__ Vt) {
  long long idx = (long long)blockIdx.x * 256 + threadIdx.x;
  const long long total = (long long)384 * 8 * 64 * 224;
  if (idx >= total) return;
  int k = (int)(idx % 224);
  long long t = idx / 224;
  int d = (int)(t % 64);
  t /= 64;
  int fr = (int)(t % 8);
  int bh = (int)(t / 8);
  bf16 v = (bf16)0.0f;
  if (k < 196) v = Vb[((long long)bh * 1568 + fr * 196 + k) * 64 + d];
  Vt[idx] = v;
}

// ---------------------------------------------------------------------------
// m97-style bf16 MFMA GEMM: C(MxN) = A(MxK) * Bt(NxK)^T. A is bf16.
// 128x128 tile, BK=64, global_load_lds width-16 staging, XOR-swizzled LDS.
// MODE 0: C = bf16 q, scaled by 0.125
// MODE 1: C -> Kb (cols<768), C2 -> Vb (cols>=768), heads layout
// MODE 2: C = f32 out + bias
template <int MODE>
__global__ __launch_bounds__(256) void gemm_k(const bf16* __restrict__ A,
                                              const bf16* __restrict__ Bt,
                                              void* __restrict__ Cptr,
                                              bf16* __restrict__ C2,
                                              const float* __restrict__ bias,
                                              int M, int N, int K) {
  __shared__ bf16 As[128 * 64];  // pitch 64 elems (contiguous: required by DMA)
  __shared__ bf16 Bs[128 * 64];
  const int tid = threadIdx.x;
  const int lane = tid & 63, w = tid >> 6;
  const int wm = w & 1, wn = w >> 1;
  const int col = lane & 15, quad = lane >> 4;
  const int m0 = blockIdx.x * 128, n0 = blockIdx.y * 128;

  const int rsub = lane >> 3;
  const int segg = (lane & 7) ^ rsub;
  const bf16* Ag0 = A + (long long)(m0 + w * 32 + rsub) * K + segg * 8;
  const bf16* Bg0 = Bt + (long long)(n0 + w * 32 + rsub) * K + segg * 8;
  bf16* Al0 = As + (w * 32) * 64;  // wave-uniform LDS base (HW adds lane*16B)
  bf16* Bl0 = Bs + (w * 32) * 64;

  f32x4 acc[4][4] = {};
  const int sA = col & 7;  // swizzle term for this lane's A/B fragment rows

  for (int k0 = 0; k0 < K; k0 += 64) {
    __syncthreads();
#pragma unroll
    for (int j = 0; j < 4; ++j)
      gload_lds16(Ag0 + (long long)j * 8 * K + k0, Al0 + j * 8 * 64);
#pragma unroll
    for (int j = 0; j < 4; ++j)
      gload_lds16(Bg0 + (long long)j * 8 * K + k0, Bl0 + j * 8 * 64);
    __syncthreads();

#pragma unroll
    for (int kk2 = 0; kk2 < 2; ++kk2) {
      const int s = kk2 * 4 + quad;     // global k-segment this frag needs
      const int slot = (s ^ sA) * 8;    // swizzled LDS chunk
      bf16x8 af[4], bfr[4];
#pragma unroll
      for (int mt = 0; mt < 4; ++mt)
        af[mt] = *(const bf16x8*)&As[(wm * 64 + mt * 16 + col) * 64 + slot];
#pragma unroll
      for (int nt = 0; nt < 4; ++nt)
        bfr[nt] = *(const bf16x8*)&Bs[(wn * 64 + nt * 16 + col) * 64 + slot];
#pragma unroll
      for (int mt = 0; mt < 4; ++mt) {
#pragma unroll
        for (int nt = 0; nt < 4; ++nt)
          acc[mt][nt] = MFMA16(af[mt], bfr[nt], acc[mt][nt]);
      }
    }
  }

  // Epilogue. C/D layout: col = lane&15, row = quad*4 + reg  [m89-verified]
#pragma unroll
  for (int mt = 0; mt < 4; ++mt) {
#pragma unroll
    for (int nt = 0; nt < 4; ++nt) {
      const int gn = n0 + wn * 64 + nt * 16 + col;
      float bv = 0.f;
      if (MODE == 2) bv = bias[gn];
#pragma unroll
      for (int r = 0; r < 4; ++r) {
        const int gm = m0 + wm * 64 + mt * 16 + quad * 4 + r;
        if (gm >= M) continue;
        const float v = acc[mt][nt][r];
        if (MODE == 0) {
          ((bf16*)Cptr)[(long long)gm * N + gn] = (bf16)(v * 0.125f);
        } else if (MODE == 1) {
          const int b = gm / 1568, j = gm - b * 1568;
          if (gn < 768) {
            const int hh = gn >> 6, dd = gn & 63;
            ((bf16*)Cptr)[((long long)(b * 12 + hh) * 1568 + j) * 64 + dd] = (bf16)v;
          } else {
            const int g2 = gn - 768;
            const int hh = g2 >> 6, dd = g2 & 63;
            C2[((long long)(b * 12 + hh) * 1568 + j) * 64 + dd] = (bf16)v;
          }
        } else {
          ((float*)Cptr)[(long long)gm * N + gn] = v + bv;
        }
      }
    }
  }
}

// ---------------------------------------------------------------------------
// Framed attention, swapped-QK^T 32x32 structure:
//  - one block per (bh, fr); K slice (224x64, XOR-swizzled) staged in LDS once
//  - sim^T = MFMA32(K, Q): lane (col=query, half) holds 16 key-scores; partner
//    lane^32 holds the other 16 -> softmax is a 16-reg tree + ONE shfl_xor(32)
//  - online softmax over 7 key tiles with defer-max threshold 8 (T13)
//  - P redistributed C-layout -> A-layout fully in-register (pack bf16 pairs +
//    shfl_xor(32) partner exchange): no LDS P buffer, no lgkmcnt(0) drains
//  - NOTE: softmax state (m,l) is indexed by query=col (sim^T layout), but the
//    PV accumulator rows are queries (r&3)+8*(r>>2)+4*half. Rescale factors and
//    the final 1/l must be transported col-layout -> row-layout via __shfl
//    (ds_bpermute). This was the round-1 correctness bug.
__global__ __launch_bounds__(256) void attn_k(const bf16* __restrict__ qs,
                                              const bf16* __restrict__ Kb,
                                              const bf16* __restrict__ Vt,
                                              bf16* __restrict__ Ob) {
  __shared__ bf16 Ks[224 * 64];  // 28 KB
  const int bh = blockIdx.x, fr = blockIdx.y;
  const int b = bh / 12, h = bh % 12;
  const int tid = threadIdx.x, lane = tid & 63, w = tid >> 6;
  const int col = lane & 31, half = lane >> 5;
  const bf16* Qb = qs + (long long)b * 197 * 768 + h * 64;
  const bf16* Kbase = Kb + ((long long)bh * 1568 + fr * 196) * 64;
  const bf16* Vbase = Vt + (long long)(bh * 8 + fr) * 64 * 224;

  // Stage K: 224 rows x 64 elems, 7 gload_lds16 per wave, pre-swizzled source.
  // Rows >= 196 read past the frame (valid workspace memory); masked post-MFMA.
  {
    const int rsub = lane >> 3;
    const int segg = (lane & 7) ^ rsub;
    const bf16* g0 = Kbase + (long long)(w * 56 + rsub) * 64 + segg * 8;
    bf16* l0 = Ks + (w * 56) * 64;
#pragma unroll
    for (int j = 0; j < 7; ++j)
      gload_lds16(g0 + (long long)j * 8 * 64, l0 + j * 8 * 64);
  }
  __syncthreads();

  for (int mt = w; mt < 7; mt += 4) {
    // Q B-fragments: lane holds Q[query=col][d = 16t + 8*half .. +8]
    const int qq = mt * 32 + col;
    const int tok = (qq < 196) ? qq + 1 : 196;
    const bf16* qp = Qb + (long long)tok * 768 + half * 8;
    bf16x8 qf[4];
#pragma unroll
    for (int t = 0; t < 4; ++t) qf[t] = *(const bf16x8*)(qp + 16 * t);

    f32x16 o0 = {}, o1 = {};
    float m = -1e30f, l = 0.f;

#pragma unroll 2
    for (int nt = 0; nt < 7; ++nt) {
      // V prefetch (independent of softmax; hides L2 latency under VALU)
      bf16x8 vf[4];
#pragma unroll
      for (int wdw = 0; wdw < 2; ++wdw)
#pragma unroll
        for (int dt = 0; dt < 2; ++dt)
          vf[wdw * 2 + dt] = *(const bf16x8*)(Vbase +
              (long long)(dt * 32 + col) * 224 + nt * 32 + wdw * 16 + half * 8);

      // QK^T: sim^T[key][query], 4 chained k=16 MFMAs over d=64
      f32x16 s = {};
#pragma unroll
      for (int t = 0; t < 4; ++t) {
        const int row = nt * 32 + col;
        const int sgm = 2 * t + half;
        const bf16x8 kf =
            *(const bf16x8*)&Ks[row * 64 + ((sgm ^ (row & 7)) << 3)];
        s = MFMA32(kf, qf[t], s);
      }
      // mask padded keys (only tile 6: keys 192..223, valid < 196)
      if (nt == 6) {
#pragma unroll
        for (int r = 0; r < 16; ++r) {
          if (r >= 4) s[r] = -1e30f;
          else if (half) s[r] = -1e30f;
        }
      }

      // per-lane max tree + one cross-half exchange (pair-uniform tm)
      float tm = s[0];
#pragma unroll
      for (int r = 1; r < 16; ++r) tm = fmaxf(tm, s[r]);
      tm = fmaxf(tm, __shfl_xor(tm, 32, 64));

      // online update with defer-max threshold (T13). m stays pair-uniform.
      // o rows are queries qr=(r&3)+8*(r>>2)+4*half -> transport sc via shfl.
      if (__any(tm > m + 8.f)) {
        const float mn = fmaxf(m, tm);
        const float sc = __expf(m - mn);
        l *= sc;
#pragma unroll
        for (int r = 0; r < 16; ++r) {
          const float scr = __shfl(sc, (r & 3) + 8 * (r >> 2) + 4 * half, 64);
          o0[r] *= scr;
          o1[r] *= scr;
        }
        m = mn;
      }

      // p = exp(s - m); accumulate partial denom; pack to bf16 pairs
      float ls = 0.f;
#pragma unroll
      for (int r = 0; r < 16; ++r) {
        s[r] = __expf(s[r] - m);
        ls += s[r];
      }
      l += ls;
      unsigned pk[8];
#pragma unroll
      for (int i = 0; i < 8; ++i) pk[i] = pk2(s[2 * i], s[2 * i + 1]);

      // redistribute P (C-layout -> A-layout) and accumulate PV
#pragma unroll
      for (int wdw = 0; wdw < 2; ++wdw) {
        // consumer half H needs keys 16*wdw + 8*H + 0..7:
        //   words 0,1 from half-0 owner's pk[2*(2w+H)], pk[2*(2w+H)+1]
        //   words 2,3 from half-1 owner's pk[2*(2w+H)], pk[2*(2w+H)+1]
        const unsigned xa = half ? pk[4 * wdw + 0] : pk[4 * wdw + 2];
        const unsigned xb = half ? pk[4 * wdw + 1] : pk[4 * wdw + 3];
        const unsigned ya = __shfl_xor(xa, 32, 64);
        const unsigned yb = __shfl_xor(xb, 32, 64);
        const unsigned oa = half ? pk[4 * wdw + 2] : pk[4 * wdw + 0];
        const unsigned ob = half ? pk[4 * wdw + 3] : pk[4 * wdw + 1];
        u32x4 wv;
        wv[0] = half ? ya : oa;
        wv[1] = half ? yb : ob;
        wv[2] = half ? oa : ya;
        wv[3] = half ? ob : yb;
        const bf16x8 pa = __builtin_bit_cast(bf16x8, wv);
        o0 = MFMA32(pa, vf[wdw * 2 + 0], o0);
        o1 = MFMA32(pa, vf[wdw * 2 + 1], o1);
      }
    }

    // epilogue: combine denominator across halves (pair-uniform), transport
    // 1/l to row layout, normalize, store
    const float lt = l + __shfl_xor(l, 32, 64);
    const float inv = 1.f / lt;
#pragma unroll
    for (int r = 0; r < 16; ++r) {
      const int qr = (r & 3) + 8 * (r >> 2) + 4 * half;
      const float invr = __shfl(inv, qr, 64);
      const int q2 = mt * 32 + qr;
      if (q2 < 196) {
        const int token = 1 + fr * 196 + q2;
        bf16* op = Ob + ((long long)b * 1569 + token) * 768 + h * 64 + col;
        op[0] = (bf16)(o0[r] * invr);
        op[32] = (bf16)(o1[r] * invr);
      }
    }
  }
}

// ---------------------------------------------------------------------------
// cls-token attention: one block per (b,h); 1 query over all 1568 keys.
__global__ __launch_bounds__(256) void cls_k(const bf16* __restrict__ qs,
                                             const bf16* __restrict__ Kb,
                                             const bf16* __restrict__ Vt,
                                             bf16* __restrict__ Ob) {
  __shared__ float qsm[64];
  __shared__ float ssm[1568];
  __shared__ float red[256];
  __shared__ float osm[4][64];
  const int bh = blockIdx.x;
  const int b = bh / 12, h = bh % 12;
  const int tid = threadIdx.x;
  if (tid < 64) qsm[tid] = (float)qs[(long long)b * 197 * 768 + h * 64 + tid];
  __syncthreads();

  float lmax = -1e30f;
  for (int j = tid; j < 1568; j += 256) {
    const bf16* kp = Kb + ((long long)bh * 1568 + j) * 64;
    float s = 0.f;
#pragma unroll
    for (int seg = 0; seg < 8; ++seg) {
      const bf16x8 kv = *(const bf16x8*)(kp + seg * 8);
#pragma unroll
      for (int i = 0; i < 8; ++i) s += qsm[seg * 8 + i] * (float)kv[i];
    }
    ssm[j] = s;
    lmax = fmaxf(lmax, s);
  }
  red[tid] = lmax;
  __syncthreads();
  for (int sft = 128; sft > 0; sft >>= 1) {
    if (tid < sft) red[tid] = fmaxf(red[tid], red[tid + sft]);
    __syncthreads();
  }
  const float mx = red[0];
  __syncthreads();

  float lsum = 0.f;
  for (int j = tid; j < 1568; j += 256) {
    const float p = __expf(ssm[j] - mx);
    ssm[j] = p;
    lsum += p;
  }
  red[tid] = lsum;
  __syncthreads();
  for (int sft = 128; sft > 0; sft >>= 1) {
    if (tid < sft) red[tid] += red[tid + sft];
    __syncthreads();
  }
  const float inv = 1.f / red[0];
  __syncthreads();

  const int d = tid & 63, c = tid >> 6;
  float acc = 0.f;
  for (int fr = c * 2; fr < c * 2 + 2; ++fr) {
    const bf16* vp = Vt + ((long long)(bh * 8 + fr) * 64 + d) * 224;
    const float* pp = &ssm[fr * 196];
    for (int k = 0; k < 196; ++k) acc += pp[k] * (float)vp[k];
  }
  osm[c][d] = acc;
  __syncthreads();
  if (tid < 64) {
    const float o = (osm[0][tid] + osm[1][tid] + osm[2][tid] + osm[3][tid]) * inv;
    Ob[(long long)b * 1569 * 768 + h * 64 + tid] = (bf16)o;
  }
}

// ---------------------------------------------------------------------------
extern "C" void kernel_launch(void* const* d_in, const int* in_sizes, int n_in,
                              void* d_out, int out_size, void* d_ws, size_t ws_size,
                              hipStream_t stream) {
  const float* x        = (const float*)d_in[0];
  const float* question = (const float*)d_in[1];
  const float* Wq       = (const float*)d_in[2];
  const float* Wkv      = (const float*)d_in[3];
  const float* Wproj    = (const float*)d_in[4];
  const float* bproj    = (const float*)d_in[5];
  float* out = (float*)d_out;

  char* wsb = (char*)d_ws;
  const long long SZ_WQT  = 768LL * 768 * 2;
  const long long SZ_WKVT = 1536LL * 768 * 2;
  const long long SZ_WPT  = 768LL * 768 * 2;
  const long long SZ_QNB  = 32LL * 197 * 768 * 2;   // question bf16
  const long long SZ_Q    = 32LL * 197 * 768 * 2;   // q (scaled) bf16
  const long long SZ_K    = 384LL * 1568 * 64 * 2;
  const long long SZ_VO   = 50208LL * 768 * 2;      // max(Vb, Ob): Ob aliases Vb

  long long off = 0;
  bf16* Wqt  = (bf16*)(wsb + off); off += SZ_WQT;
  bf16* Wkvt = (bf16*)(wsb + off); off += SZ_WKVT;
  bf16* Wpt  = (bf16*)(wsb + off); off += SZ_WPT;
  bf16* qnb  = (bf16*)(wsb + off); off += SZ_QNB;
  bf16* qsb  = (bf16*)(wsb + off); off += SZ_Q;
  bf16* Kb   = (bf16*)(wsb + off); off += SZ_K;
  bf16* Vb   = (bf16*)(wsb + off); off += SZ_VO;
  bf16* Ob   = Vb;                     // alias: Vb dead after transv_k
  // xb (bf16 x, 77 MB) and Vt (88 MB) share one region: xb dead before transv.
  bf16* xb   = (bf16*)(wsb + off);
  bf16* Vt   = (bf16*)(wsb + off);

  const long long nx = 32LL * 1568 * 768;
  const long long nq = 32LL * 197 * 768;
  f2b_k<<<(int)((nx / 8 + 255) / 256), 256, 0, stream>>>(x, xb, nx);
  f2b_k<<<(int)((nq / 8 + 255) / 256), 256, 0, stream>>>(question, qnb, nq);

  wconv_k<<<(768 * 768) / 256, 256, 0, stream>>>(Wq, Wqt, 768, 768);
  wconv_k<<<(768 * 1536) / 256, 256, 0, stream>>>(Wkv, Wkvt, 768, 1536);
  wconv_k<<<(768 * 768) / 256, 256, 0, stream>>>(Wproj, Wpt, 768, 768);

  // q = (question @ Wq) * 0.125, bf16
  gemm_k<0><<<dim3(50, 6), 256, 0, stream>>>(qnb, Wqt, qsb, nullptr, nullptr,
                                             6304, 768, 768);
  // kv = x @ Wkv -> Kb, Vb (heads layout)
  gemm_k<1><<<dim3(392, 12), 256, 0, stream>>>(xb, Wkvt, Kb, Vb, nullptr,
                                               50176, 1536, 768);
  // V -> padded transposed layout (xb dead now; Vt overlays it)
  transv_k<<<(384 * 8 * 64 * 224) / 256, 256, 0, stream>>>(Vb, Vt);

  cls_k<<<384, 256, 0, stream>>>(qsb, Kb, Vt, Ob);
  attn_k<<<dim3(384, 8), 256, 0, stream>>>(qsb, Kb, Vt, Ob);

  // out = O @ Wproj + bproj (f32)
  gemm_k<2><<<dim3(393, 6), 256, 0, stream>>>(Ob, Wpt, out, nullptr, bproj,
                                              50208, 768, 768);
}

// Round 3
// 816.923 us; speedup vs baseline: 1.2946x; 1.1116x over previous
//
#include <hip/hip_runtime.h>

typedef __bf16 bf16;
typedef __bf16 bf16x8 __attribute__((ext_vector_type(8)));
typedef __bf16 bf16x4 __attribute__((ext_vector_type(4)));
typedef __bf16 bf16x2 __attribute__((ext_vector_type(2)));
typedef float f32x4 __attribute__((ext_vector_type(4)));
typedef float f32x16 __attribute__((ext_vector_type(16)));
typedef unsigned int u32x4 __attribute__((ext_vector_type(4)));

#define MFMA16(a, b, c) __builtin_amdgcn_mfma_f32_16x16x32_bf16(a, b, c, 0, 0, 0)
#define MFMA32(a, b, c) __builtin_amdgcn_mfma_f32_32x32x16_bf16(a, b, c, 0, 0, 0)

__device__ __forceinline__ void gload_lds16(const bf16* g, bf16* l) {
  __builtin_amdgcn_global_load_lds(
      (const __attribute__((address_space(1))) void*)g,
      (__attribute__((address_space(3))) void*)l, 16, 0, 0);
}

__device__ __forceinline__ unsigned pk2(float a, float b) {
  bf16x2 t;
  t[0] = (bf16)a;
  t[1] = (bf16)b;
  return __builtin_bit_cast(unsigned, t);
}

// ---------------------------------------------------------------------------
// f32 -> bf16 bulk convert, 8 elems/thread (32B load, 16B store)
__global__ __launch_bounds__(256) void f2b_k(const float* __restrict__ src,
                                             bf16* __restrict__ dst,
                                             long long n) {
  long long i = ((long long)blockIdx.x * 256 + threadIdx.x) * 8;
  if (i >= n) return;
  const float4 a = *(const float4*)(src + i);
  const float4 b = *(const float4*)(src + i + 4);
  bf16x8 v;
  v[0] = (bf16)a.x; v[1] = (bf16)a.y; v[2] = (bf16)a.z; v[3] = (bf16)a.w;
  v[4] = (bf16)b.x; v[5] = (bf16)b.y; v[6] = (bf16)b.z; v[7] = (bf16)b.w;
  *(bf16x8*)(dst + i) = v;
}

// ---------------------------------------------------------------------------
// Weight transpose+convert: Wt[n*K + k] = (bf16) W[k*N + n]
__global__ __launch_bounds__(256) void wconv_k(const float* __restrict__ W,
                                               bf16* __restrict__ Wt,
                                               int K, int N) {
  long long idx = (long long)blockIdx.x * 256 + threadIdx.x;
  if (idx >= (long long)K * N) return;
  int k = (int)(idx % K);
  int n = (int)(idx / K);
  Wt[idx] = (bf16)W[(long long)k * N + n];
}

// ---------------------------------------------------------------------------
// Zero the Vt padding stripes k in [196,224) (attn PV multiplies P=0 by these;
// must be finite). Was previously done by transv_k's zero-fill.
__global__ __launch_bounds__(256) void pad0_k(bf16* __restrict__ Vt) {
  long long idx = (long long)blockIdx.x * 256 + threadIdx.x;
  const long long total = 3072LL * 64 * 7;  // frames * d * (28/4) chunks
  if (idx >= total) return;
  int c = (int)(idx % 7);
  long long t = idx / 7;
  int d = (int)(t % 64);
  long long f = t / 64;
  bf16x4 z = {};
  *(bf16x4*)&Vt[(f * 64 + d) * 224 + 196 + c * 4] = z;
}

// ---------------------------------------------------------------------------
// m97-style 128x128 bf16 MFMA GEMM (kept for the small q projection).
// MODE 0: C = bf16 q, scaled by 0.125
template <int MODE>
__global__ __launch_bounds__(256) void gemm_k(const bf16* __restrict__ A,
                                              const bf16* __restrict__ Bt,
                                              void* __restrict__ Cptr,
                                              const float* __restrict__ bias,
                                              int M, int N, int K) {
  __shared__ bf16 As[128 * 64];
  __shared__ bf16 Bs[128 * 64];
  const int tid = threadIdx.x;
  const int lane = tid & 63, w = tid >> 6;
  const int wm = w & 1, wn = w >> 1;
  const int col = lane & 15, quad = lane >> 4;
  const int m0 = blockIdx.x * 128, n0 = blockIdx.y * 128;

  const int rsub = lane >> 3;
  const int segg = (lane & 7) ^ rsub;
  const bf16* Ag0 = A + (long long)(m0 + w * 32 + rsub) * K + segg * 8;
  const bf16* Bg0 = Bt + (long long)(n0 + w * 32 + rsub) * K + segg * 8;
  bf16* Al0 = As + (w * 32) * 64;
  bf16* Bl0 = Bs + (w * 32) * 64;

  f32x4 acc[4][4] = {};
  const int sA = col & 7;

  for (int k0 = 0; k0 < K; k0 += 64) {
    __syncthreads();
#pragma unroll
    for (int j = 0; j < 4; ++j)
      gload_lds16(Ag0 + (long long)j * 8 * K + k0, Al0 + j * 8 * 64);
#pragma unroll
    for (int j = 0; j < 4; ++j)
      gload_lds16(Bg0 + (long long)j * 8 * K + k0, Bl0 + j * 8 * 64);
    __syncthreads();

#pragma unroll
    for (int kk2 = 0; kk2 < 2; ++kk2) {
      const int s = kk2 * 4 + quad;
      const int slot = (s ^ sA) * 8;
      bf16x8 af[4], bfr[4];
#pragma unroll
      for (int mt = 0; mt < 4; ++mt)
        af[mt] = *(const bf16x8*)&As[(wm * 64 + mt * 16 + col) * 64 + slot];
#pragma unroll
      for (int nt = 0; nt < 4; ++nt)
        bfr[nt] = *(const bf16x8*)&Bs[(wn * 64 + nt * 16 + col) * 64 + slot];
#pragma unroll
      for (int mt = 0; mt < 4; ++mt) {
#pragma unroll
        for (int nt = 0; nt < 4; ++nt)
          acc[mt][nt] = MFMA16(af[mt], bfr[nt], acc[mt][nt]);
      }
    }
  }

#pragma unroll
  for (int mt = 0; mt < 4; ++mt) {
#pragma unroll
    for (int nt = 0; nt < 4; ++nt) {
      const int gn = n0 + wn * 64 + nt * 16 + col;
#pragma unroll
      for (int r = 0; r < 4; ++r) {
        const int gm = m0 + wm * 64 + mt * 16 + quad * 4 + r;
        if (gm >= M) continue;
        const float v = acc[mt][nt][r];
        ((bf16*)Cptr)[(long long)gm * N + gn] = (bf16)(v * 0.125f);
      }
    }
  }
}

// ---------------------------------------------------------------------------
// 256x256 / BK=64 / 8-wave GEMM, double-buffered LDS (128 KiB), minimal
// 2-phase pipeline (T3 recipe): stage tile t+1 BEFORE computing tile t, one
// __syncthreads per K-step (compiler's vmcnt(0) drain lands after the loads
// had the whole compute phase to fly). Bijective XCD swizzle (m204), n-tile
// fastest within an XCD chunk for A-panel L2 reuse.
// MODE 1: C -> Kb (cols<768, heads layout), C2 -> Vt (cols>=768, fused
//         transpose to padded per-frame layout, bf16x4 stores)
// MODE 2: C = f32 out + bias
template <int MODE>
__global__ __launch_bounds__(512) void gemm256_k(
    const bf16* __restrict__ A, const bf16* __restrict__ Bt,
    void* __restrict__ Cptr, bf16* __restrict__ C2,
    const float* __restrict__ bias, int M, int N, int K,
    int NB, int qq, int rq) {
  __shared__ bf16 As[2][256 * 64];
  __shared__ bf16 Bs[2][256 * 64];
  const int tid = threadIdx.x;
  const int lane = tid & 63, w = tid >> 6;
  const int wm = w & 1, wn = w >> 1;
  const int col = lane & 15, quad = lane >> 4;

  // bijective XCD swizzle: xcd = bid%8 owns a contiguous wg chunk; within the
  // chunk nb varies fastest so blocks sharing an A panel are co-resident.
  const int bid = blockIdx.x;
  const int xcd = bid & 7, ii = bid >> 3;
  const int wg = (xcd < rq ? xcd * (qq + 1) : rq * (qq + 1) + (xcd - rq) * qq) + ii;
  const int mb = wg / NB, nb = wg - mb * NB;
  const int m0 = mb * 256, n0 = nb * 256;

  const int rsub = lane >> 3;
  const int segg = (lane & 7) ^ rsub;  // pre-swizzled global source chunk
  const bf16* Ag0 = A + (long long)(m0 + w * 32 + rsub) * K + segg * 8;
  const bf16* Bg0 = Bt + (long long)(n0 + w * 32 + rsub) * K + segg * 8;
  const int lbase = (w * 32) * 64;

  f32x4 acc[8][4] = {};
  const int sA = col & 7;

  // prologue: stage tile 0 into buffer 0
#pragma unroll
  for (int j = 0; j < 4; ++j) {
    gload_lds16(Ag0 + (long long)j * 8 * K, &As[0][lbase + j * 8 * 64]);
    gload_lds16(Bg0 + (long long)j * 8 * K, &Bs[0][lbase + j * 8 * 64]);
  }
  __syncthreads();

  for (int k0 = 0; k0 < K; k0 += 64) {
    const int cur = (k0 >> 6) & 1;
    if (k0 + 64 < K) {  // stage next tile; loads fly under this tile's MFMAs
#pragma unroll
      for (int j = 0; j < 4; ++j) {
        gload_lds16(Ag0 + (long long)j * 8 * K + k0 + 64,
                    &As[cur ^ 1][lbase + j * 8 * 64]);
        gload_lds16(Bg0 + (long long)j * 8 * K + k0 + 64,
                    &Bs[cur ^ 1][lbase + j * 8 * 64]);
      }
    }
#pragma unroll
    for (int kk2 = 0; kk2 < 2; ++kk2) {
      const int slot = ((kk2 * 4 + quad) ^ sA) << 3;
      bf16x8 af[8], bfv[4];
#pragma unroll
      for (int mt = 0; mt < 8; ++mt)
        af[mt] = *(const bf16x8*)&As[cur][(wm * 128 + mt * 16 + col) * 64 + slot];
#pragma unroll
      for (int nt = 0; nt < 4; ++nt)
        bfv[nt] = *(const bf16x8*)&Bs[cur][(wn * 64 + nt * 16 + col) * 64 + slot];
#pragma unroll
      for (int mt = 0; mt < 8; ++mt) {
#pragma unroll
        for (int nt = 0; nt < 4; ++nt)
          acc[mt][nt] = MFMA16(af[mt], bfv[nt], acc[mt][nt]);
      }
    }
    __syncthreads();  // releases buf cur for overwrite; drains next-tile loads
  }

  // Epilogue. C/D layout: col = lane&15, row = quad*4 + r  [m89-verified]
  if (MODE == 1) {
    bf16* Kbp = (bf16*)Cptr;
#pragma unroll
    for (int mt = 0; mt < 8; ++mt) {
      const int gm0 = m0 + wm * 128 + mt * 16 + quad * 4;  // 4-aligned
      if (gm0 >= M) continue;
      // group of 4 rows never straddles a b (1568) or frame (196) boundary
      const int bb = gm0 / 1568;
      const int j0 = gm0 - bb * 1568;
      const int fr = j0 / 196;
      const int kk0 = j0 - fr * 196;
#pragma unroll
      for (int nt = 0; nt < 4; ++nt) {
        const int gn = n0 + wn * 64 + nt * 16 + col;
        if (gn < 768) {  // K output, heads layout (wave-uniform branch)
          const int hh = gn >> 6, dd = gn & 63;
          bf16* kp = Kbp + ((long long)(bb * 12 + hh) * 1568 + j0) * 64 + dd;
#pragma unroll
          for (int r = 0; r < 4; ++r) kp[r * 64] = (bf16)acc[mt][nt][r];
        } else {  // V output, fused transpose into padded Vt; contiguous k
          const int g2 = gn - 768;
          const int hh = g2 >> 6, dd = g2 & 63;
          bf16x4 pv;
          pv[0] = (bf16)acc[mt][nt][0];
          pv[1] = (bf16)acc[mt][nt][1];
          pv[2] = (bf16)acc[mt][nt][2];
          pv[3] = (bf16)acc[mt][nt][3];
          *(bf16x4*)&C2[(((long long)(bb * 12 + hh) * 8 + fr) * 64 + dd) * 224 +
                        kk0] = pv;
        }
      }
    }
  } else {  // MODE 2: f32 out + bias
#pragma unroll
    for (int mt = 0; mt < 8; ++mt) {
#pragma unroll
      for (int nt = 0; nt < 4; ++nt) {
        const int gn = n0 + wn * 64 + nt * 16 + col;
        const float bv = bias[gn];
#pragma unroll
        for (int r = 0; r < 4; ++r) {
          const int gm = m0 + wm * 128 + mt * 16 + quad * 4 + r;
          if (gm < M)
            ((float*)Cptr)[(long long)gm * N + gn] = acc[mt][nt][r] + bv;
        }
      }
    }
  }
}

// ---------------------------------------------------------------------------
// Framed attention, swapped-QK^T 32x32 structure (round-2 verified).
__global__ __launch_bounds__(256) void attn_k(const bf16* __restrict__ qs,
                                              const bf16* __restrict__ Kb,
                                              const bf16* __restrict__ Vt,
                                              bf16* __restrict__ Ob) {
  __shared__ bf16 Ks[224 * 64];  // 28 KB
  const int bh = blockIdx.x, fr = blockIdx.y;
  const int b = bh / 12, h = bh % 12;
  const int tid = threadIdx.x, lane = tid & 63, w = tid >> 6;
  const int col = lane & 31, half = lane >> 5;
  const bf16* Qb = qs + (long long)b * 197 * 768 + h * 64;
  const bf16* Kbase = Kb + ((long long)bh * 1568 + fr * 196) * 64;
  const bf16* Vbase = Vt + (long long)(bh * 8 + fr) * 64 * 224;

  {
    const int rsub = lane >> 3;
    const int segg = (lane & 7) ^ rsub;
    const bf16* g0 = Kbase + (long long)(w * 56 + rsub) * 64 + segg * 8;
    bf16* l0 = Ks + (w * 56) * 64;
#pragma unroll
    for (int j = 0; j < 7; ++j)
      gload_lds16(g0 + (long long)j * 8 * 64, l0 + j * 8 * 64);
  }
  __syncthreads();

  for (int mt = w; mt < 7; mt += 4) {
    const int qq = mt * 32 + col;
    const int tok = (qq < 196) ? qq + 1 : 196;
    const bf16* qp = Qb + (long long)tok * 768 + half * 8;
    bf16x8 qf[4];
#pragma unroll
    for (int t = 0; t < 4; ++t) qf[t] = *(const bf16x8*)(qp + 16 * t);

    f32x16 o0 = {}, o1 = {};
    float m = -1e30f, l = 0.f;

#pragma unroll 2
    for (int nt = 0; nt < 7; ++nt) {
      bf16x8 vf[4];
#pragma unroll
      for (int wdw = 0; wdw < 2; ++wdw)
#pragma unroll
        for (int dt = 0; dt < 2; ++dt)
          vf[wdw * 2 + dt] = *(const bf16x8*)(Vbase +
              (long long)(dt * 32 + col) * 224 + nt * 32 + wdw * 16 + half * 8);

      f32x16 s = {};
#pragma unroll
      for (int t = 0; t < 4; ++t) {
        const int row = nt * 32 + col;
        const int sgm = 2 * t + half;
        const bf16x8 kf =
            *(const bf16x8*)&Ks[row * 64 + ((sgm ^ (row & 7)) << 3)];
        s = MFMA32(kf, qf[t], s);
      }
      if (nt == 6) {
#pragma unroll
        for (int r = 0; r < 16; ++r) {
          if (r >= 4) s[r] = -1e30f;
          else if (half) s[r] = -1e30f;
        }
      }

      float tm = s[0];
#pragma unroll
      for (int r = 1; r < 16; ++r) tm = fmaxf(tm, s[r]);
      tm = fmaxf(tm, __shfl_xor(tm, 32, 64));

      if (__any(tm > m + 8.f)) {
        const float mn = fmaxf(m, tm);
        const float sc = __expf(m - mn);
        l *= sc;
#pragma unroll
        for (int r = 0; r < 16; ++r) {
          const float scr = __shfl(sc, (r & 3) + 8 * (r >> 2) + 4 * half, 64);
          o0[r] *= scr;
          o1[r] *= scr;
        }
        m = mn;
      }

      float ls = 0.f;
#pragma unroll
      for (int r = 0; r < 16; ++r) {
        s[r] = __expf(s[r] - m);
        ls += s[r];
      }
      l += ls;
      unsigned pk[8];
#pragma unroll
      for (int i = 0; i < 8; ++i) pk[i] = pk2(s[2 * i], s[2 * i + 1]);

#pragma unroll
      for (int wdw = 0; wdw < 2; ++wdw) {
        const unsigned xa = half ? pk[4 * wdw + 0] : pk[4 * wdw + 2];
        const unsigned xb = half ? pk[4 * wdw + 1] : pk[4 * wdw + 3];
        const unsigned ya = __shfl_xor(xa, 32, 64);
        const unsigned yb = __shfl_xor(xb, 32, 64);
        const unsigned oa = half ? pk[4 * wdw + 2] : pk[4 * wdw + 0];
        const unsigned ob = half ? pk[4 * wdw + 3] : pk[4 * wdw + 1];
        u32x4 wv;
        wv[0] = half ? ya : oa;
        wv[1] = half ? yb : ob;
        wv[2] = half ? oa : ya;
        wv[3] = half ? ob : yb;
        const bf16x8 pa = __builtin_bit_cast(bf16x8, wv);
        o0 = MFMA32(pa, vf[wdw * 2 + 0], o0);
        o1 = MFMA32(pa, vf[wdw * 2 + 1], o1);
      }
    }

    const float lt = l + __shfl_xor(l, 32, 64);
    const float inv = 1.f / lt;
#pragma unroll
    for (int r = 0; r < 16; ++r) {
      const int qr = (r & 3) + 8 * (r >> 2) + 4 * half;
      const float invr = __shfl(inv, qr, 64);
      const int q2 = mt * 32 + qr;
      if (q2 < 196) {
        const int token = 1 + fr * 196 + q2;
        bf16* op = Ob + ((long long)b * 1569 + token) * 768 + h * 64 + col;
        op[0] = (bf16)(o0[r] * invr);
        op[32] = (bf16)(o1[r] * invr);
      }
    }
  }
}

// ---------------------------------------------------------------------------
// cls-token attention: one block per (b,h); 1 query over all 1568 keys.
__global__ __launch_bounds__(256) void cls_k(const bf16* __restrict__ qs,
                                             const bf16* __restrict__ Kb,
                                             const bf16* __restrict__ Vt,
                                             bf16* __restrict__ Ob) {
  __shared__ float qsm[64];
  __shared__ float ssm[1568];
  __shared__ float red[256];
  __shared__ float osm[4][64];
  const int bh = blockIdx.x;
  const int b = bh / 12, h = bh % 12;
  const int tid = threadIdx.x;
  if (tid < 64) qsm[tid] = (float)qs[(long long)b * 197 * 768 + h * 64 + tid];
  __syncthreads();

  float lmax = -1e30f;
  for (int j = tid; j < 1568; j += 256) {
    const bf16* kp = Kb + ((long long)bh * 1568 + j) * 64;
    float s = 0.f;
#pragma unroll
    for (int seg = 0; seg < 8; ++seg) {
      const bf16x8 kv = *(const bf16x8*)(kp + seg * 8);
#pragma unroll
      for (int i = 0; i < 8; ++i) s += qsm[seg * 8 + i] * (float)kv[i];
    }
    ssm[j] = s;
    lmax = fmaxf(lmax, s);
  }
  red[tid] = lmax;
  __syncthreads();
  for (int sft = 128; sft > 0; sft >>= 1) {
    if (tid < sft) red[tid] = fmaxf(red[tid], red[tid + sft]);
    __syncthreads();
  }
  const float mx = red[0];
  __syncthreads();

  float lsum = 0.f;
  for (int j = tid; j < 1568; j += 256) {
    const float p = __expf(ssm[j] - mx);
    ssm[j] = p;
    lsum += p;
  }
  red[tid] = lsum;
  __syncthreads();
  for (int sft = 128; sft > 0; sft >>= 1) {
    if (tid < sft) red[tid] += red[tid + sft];
    __syncthreads();
  }
  const float inv = 1.f / red[0];
  __syncthreads();

  const int d = tid & 63, c = tid >> 6;
  float acc = 0.f;
  for (int fr = c * 2; fr < c * 2 + 2; ++fr) {
    const bf16* vp = Vt + ((long long)(bh * 8 + fr) * 64 + d) * 224;
    const float* pp = &ssm[fr * 196];
    for (int k = 0; k < 196; ++k) acc += pp[k] * (float)vp[k];
  }
  osm[c][d] = acc;
  __syncthreads();
  if (tid < 64) {
    const float o = (osm[0][tid] + osm[1][tid] + osm[2][tid] + osm[3][tid]) * inv;
    Ob[(long long)b * 1569 * 768 + h * 64 + tid] = (bf16)o;
  }
}

// ---------------------------------------------------------------------------
extern "C" void kernel_launch(void* const* d_in, const int* in_sizes, int n_in,
                              void* d_out, int out_size, void* d_ws, size_t ws_size,
                              hipStream_t stream) {
  const float* x        = (const float*)d_in[0];
  const float* question = (const float*)d_in[1];
  const float* Wq       = (const float*)d_in[2];
  const float* Wkv      = (const float*)d_in[3];
  const float* Wproj    = (const float*)d_in[4];
  const float* bproj    = (const float*)d_in[5];
  float* out = (float*)d_out;

  char* wsb = (char*)d_ws;
  const long long SZ_WQT  = 768LL * 768 * 2;
  const long long SZ_WKVT = 1536LL * 768 * 2;
  const long long SZ_WPT  = 768LL * 768 * 2;
  const long long SZ_QNB  = 32LL * 197 * 768 * 2;   // question bf16
  const long long SZ_Q    = 32LL * 197 * 768 * 2;   // q (scaled) bf16
  const long long SZ_XO   = 50208LL * 768 * 2;      // max(xb, Ob); Ob aliases xb
  const long long SZ_K    = 384LL * 1568 * 64 * 2;  // K heads layout
  // Vt (88 MB) gets its own region now (no Vb): total ~266 MB, same as before.

  long long off = 0;
  bf16* Wqt  = (bf16*)(wsb + off); off += SZ_WQT;
  bf16* Wkvt = (bf16*)(wsb + off); off += SZ_WKVT;
  bf16* Wpt  = (bf16*)(wsb + off); off += SZ_WPT;
  bf16* qnb  = (bf16*)(wsb + off); off += SZ_QNB;
  bf16* qsb  = (bf16*)(wsb + off); off += SZ_Q;
  bf16* xb   = (bf16*)(wsb + off);                   // A of KV gemm
  bf16* Ob   = xb;                                   // xb dead after KV gemm
  off += SZ_XO;                                      // (Ob OOB reads -> Kb: safe)
  bf16* Kb   = (bf16*)(wsb + off); off += SZ_K;
  bf16* Vt   = (bf16*)(wsb + off);

  const long long nx = 32LL * 1568 * 768;
  const long long nq = 32LL * 197 * 768;
  f2b_k<<<(int)((nx / 8 + 255) / 256), 256, 0, stream>>>(x, xb, nx);
  f2b_k<<<(int)((nq / 8 + 255) / 256), 256, 0, stream>>>(question, qnb, nq);

  wconv_k<<<(768 * 768) / 256, 256, 0, stream>>>(Wq, Wqt, 768, 768);
  wconv_k<<<(768 * 1536) / 256, 256, 0, stream>>>(Wkv, Wkvt, 768, 1536);
  wconv_k<<<(768 * 768) / 256, 256, 0, stream>>>(Wproj, Wpt, 768, 768);
  pad0_k<<<(3072 * 64 * 7) / 256, 256, 0, stream>>>(Vt);

  // q = (question @ Wq) * 0.125, bf16
  gemm_k<0><<<dim3(50, 6), 256, 0, stream>>>(qnb, Wqt, qsb, nullptr,
                                             6304, 768, 768);
  // kv = x @ Wkv -> Kb (heads layout) + Vt (fused transpose); 196x6 blocks
  gemm256_k<1><<<1176, 512, 0, stream>>>(xb, Wkvt, Kb, Vt, nullptr,
                                         50176, 1536, 768, 6, 147, 0);

  cls_k<<<384, 256, 0, stream>>>(qsb, Kb, Vt, Ob);
  attn_k<<<dim3(384, 8), 256, 0, stream>>>(qsb, Kb, Vt, Ob);

  // out = O @ Wproj + bproj (f32); 197x3 blocks (last m-block partial)
  gemm256_k<2><<<591, 512, 0, stream>>>(Ob, Wpt, out, nullptr, bproj,
                                        50208, 768, 768, 3, 73, 7);
}